// Round 9
// baseline (245.368 us; speedup 1.0000x reference)
//
#include <hip/hip_runtime.h>
#include <cstddef>

#define VOCAB  50000
#define INPUT  512
#define HIDDEN 1024
#define BATCH  64
#define MAXLEN 256
#define NBLK   1563   // gemv blocks (two 16-col tiles each) == lse partials per row

typedef float  f32x4 __attribute__((ext_vector_type(4)));
typedef __bf16 bf16x8 __attribute__((ext_vector_type(8)));

__device__ __forceinline__ bf16x8 cvt8(float4 a, float4 b) {
    bf16x8 r;
    r[0] = (__bf16)a.x; r[1] = (__bf16)a.y; r[2] = (__bf16)a.z; r[3] = (__bf16)a.w;
    r[4] = (__bf16)b.x; r[5] = (__bf16)b.y; r[6] = (__bf16)b.z; r[7] = (__bf16)b.w;
    return r;
}

// D1: blocks 0..63 -> u2 partials (hq,kc as before); blocks 64..447 -> pack emb/hid to bf16.
__global__ void k_u2_pack(const float* __restrict__ attn_W, const float* __restrict__ v,
                          float* __restrict__ u2p,
                          const int* __restrict__ last_output,
                          const float* __restrict__ embedding,
                          const float* __restrict__ hid,
                          __bf16* __restrict__ x_bf, __bf16* __restrict__ hid_bf) {
    int bid = blockIdx.x, tid = threadIdx.x;
    if (bid < 64) {
        int hq = bid >> 4, kc = bid & 15;
        int kl = tid & 63, hg = tid >> 6;
        int k = kc * 64 + kl;
        float acc = 0.f;
        int h0 = hq * 256 + hg * 64;
#pragma unroll 8
        for (int h = h0; h < h0 + 64; ++h)
            acc += v[h] * attn_W[(size_t)h * (2 * HIDDEN) + HIDDEN + k];
        __shared__ float red[4][64];
        red[hg][kl] = acc;
        __syncthreads();
        if (tid < 64)
            u2p[hq * 1024 + kc * 64 + tid] =
                red[0][tid] + red[1][tid] + red[2][tid] + red[3][tid];
    } else {
        int idx = (bid - 64) * 256 + tid;   // 98304 = 64*512 + 64*1024
        if (idx < 64 * INPUT) {
            int b = idx >> 9, k = idx & 511;
            x_bf[b * 1536 + k] = (__bf16)embedding[(size_t)last_output[b] * INPUT + k];
        } else {
            idx -= 64 * INPUT;
            int b = idx >> 10, h = idx & 1023;
            hid_bf[b * HIDDEN + h] = (__bf16)hid[b * HIDDEN + h];
        }
    }
}

// D2: fully fused attention. 256 blocks = (b, hc). Each block: all 256 scores for b
// (4 waves x 64 wave-reduced dots), exact softmax, then ctx for its 256-h chunk + pack.
// 4 blocks per b redo scores (cheap VALU; enc reads L2-shared).
__global__ __launch_bounds__(256) void k_att_full(const float* __restrict__ enc,
                                                  const float* __restrict__ u2p,
                                                  __bf16* __restrict__ x_bf,
                                                  __bf16* __restrict__ y_bf) {
    int bid = blockIdx.x, tid = threadIdx.x;
    int b = bid >> 2, hc = bid & 3;
    __shared__ float u2s[1024];
    __shared__ float s_lds[256];
    __shared__ float red[256];
    for (int i = tid; i < 1024; i += 256)
        u2s[i] = u2p[i] + u2p[1024 + i] + u2p[2048 + i] + u2p[3072 + i];
    __syncthreads();
    int w = tid >> 6, lane = tid & 63;
#pragma unroll 4
    for (int it = 0; it < 64; ++it) {
        int t = w * 64 + it;
        const float* row = enc + ((size_t)t * BATCH + b) * HIDDEN;
        float acc = 0.f;
#pragma unroll
        for (int i = 0; i < 4; ++i) {
            float4 e = *(const float4*)(row + lane * 4 + i * 256);
            float4 u = *(const float4*)(&u2s[lane * 4 + i * 256]);
            acc += e.x * u.x + e.y * u.y + e.z * u.z + e.w * u.w;
        }
#pragma unroll
        for (int off = 32; off; off >>= 1) acc += __shfl_down(acc, off, 64);
        if (lane == 0) s_lds[t] = acc;
    }
    __syncthreads();
    // softmax over 256 (exact, block-local)
    float sv = s_lds[tid];
    red[tid] = sv; __syncthreads();
    for (int off = 128; off; off >>= 1) { if (tid < off) red[tid] = fmaxf(red[tid], red[tid + off]); __syncthreads(); }
    float m = red[0]; __syncthreads();
    float e = expf(sv - m);
    red[tid] = e; __syncthreads();
    for (int off = 128; off; off >>= 1) { if (tid < off) red[tid] += red[tid + off]; __syncthreads(); }
    s_lds[tid] = e * (1.f / red[0]);    // attn weights
    __syncthreads();
    int h = hc * 256 + tid;
    float acc = 0.f;
#pragma unroll 8
    for (int t = 0; t < MAXLEN; ++t)
        acc += s_lds[t] * enc[((size_t)(t * BATCH + b)) * HIDDEN + h];
    x_bf[b * 1536 + INPUT + h]  = (__bf16)acc;
    y_bf[b * 2048 + HIDDEN + h] = (__bf16)acc;
}

// Small-M GEMM tile body: out[64, jt*16..+16] = A[64,K] @ W[N,K]^T + bias.
__device__ __forceinline__ void gemm_tile(const float* __restrict__ W,
                                          const float* __restrict__ bias,
                                          const __bf16* __restrict__ A,
                                          float* __restrict__ out,
                                          int N, int K, int jt, int tid) {
    int wid = tid >> 6, lane = tid & 63;
    int j  = jt * 16 + (lane & 15);
    int kg = (lane >> 4) * 8;
    int kchunk = K >> 2;
    int kbeg = wid * kchunk, kend = kbeg + kchunk;
    const float*  wrow = W + (size_t)j * K;
    const __bf16* arow = A + (size_t)(lane & 15) * K;
    f32x4 acc[4] = {};
    for (int k0 = kbeg; k0 < kend; k0 += 32) {
        int kk = k0 + kg;
        float4 w0 = *(const float4*)(wrow + kk);
        float4 w1 = *(const float4*)(wrow + kk + 4);
        bf16x8 bw = cvt8(w0, w1);
#pragma unroll
        for (int mt = 0; mt < 4; ++mt) {
            bf16x8 av = *(const bf16x8*)(arow + (size_t)mt * 16 * K + kk);
            acc[mt] = __builtin_amdgcn_mfma_f32_16x16x32_bf16(av, bw, acc[mt], 0, 0, 0);
        }
    }
    __shared__ float lds[4][1024];
#pragma unroll
    for (int mt = 0; mt < 4; ++mt)
#pragma unroll
        for (int r = 0; r < 4; ++r) {
            int m = mt * 16 + (lane >> 4) * 4 + r;
            lds[wid][m * 16 + (lane & 15)] = acc[mt][r];
        }
    __syncthreads();
#pragma unroll
    for (int o = tid; o < 1024; o += 256) {
        float s = lds[0][o] + lds[1][o] + lds[2][o] + lds[3][o];
        int m = o >> 4, jl = o & 15;
        out[(size_t)m * N + jt * 16 + jl] = s + bias[jt * 16 + jl];
    }
}

// GRU gate GEMMs, one dispatch: blocks 0..191 -> Gi (K=1536), 192..383 -> Gh (K=1024)
__global__ __launch_bounds__(256) void k_gemm_gru(const float* __restrict__ W_ih,
                                                  const float* __restrict__ b_ih,
                                                  const __bf16* __restrict__ x_bf,
                                                  float* __restrict__ Gi,
                                                  const float* __restrict__ W_hh,
                                                  const float* __restrict__ b_hh,
                                                  const __bf16* __restrict__ hid_bf,
                                                  float* __restrict__ Gh) {
    int bid = blockIdx.x, tid = threadIdx.x;
    if (bid < 192) gemm_tile(W_ih, b_ih, x_bf,  Gi, 3072, 1536, bid,       tid);
    else           gemm_tile(W_hh, b_hh, hid_bf, Gh, 3072, 1024, bid - 192, tid);
}

// GRU combine: h_new = (1-z)*n + z*h_prev
__global__ void k_combine(const float* __restrict__ Gi, const float* __restrict__ Gh,
                          const float* __restrict__ hid, float* __restrict__ hnew_out,
                          __bf16* __restrict__ y_bf) {
    int idx = blockIdx.x * 256 + threadIdx.x;   // 64*1024
    int b = idx >> 10, h = idx & 1023;
    const float* gi = Gi + (size_t)b * 3072;
    const float* gh = Gh + (size_t)b * 3072;
    float r  = 1.f / (1.f + expf(-(gi[h] + gh[h])));
    float z  = 1.f / (1.f + expf(-(gi[1024 + h] + gh[1024 + h])));
    float n  = tanhf(gi[2048 + h] + r * gh[2048 + h]);
    float hp = hid[b * HIDDEN + h];
    float hn = (1.f - z) * n + z * hp;
    hnew_out[b * HIDDEN + h] = hn;
    y_bf[b * 2048 + h] = (__bf16)hn;
}

// Vocab projection: 1563 blocks, 2 x 16-col tiles (last block 1). Plain loads (proven).
// Emits one online (max, sumexp) partial per (row, block).
__global__ __launch_bounds__(256) void k_gemv(const float* __restrict__ W,
                                              const float* __restrict__ bias,
                                              const __bf16* __restrict__ A,
                                              float* __restrict__ out,
                                              float* __restrict__ mw,
                                              float* __restrict__ sw) {
    int bid = blockIdx.x, tid = threadIdx.x;
    int wid = tid >> 6, lane = tid & 63;
    int kg = (lane >> 4) * 8;
    int kbeg = wid * 512, kend = kbeg + 512;     // K=2048 over 4 waves
    int ntiles = (bid == NBLK - 1) ? 1 : 2;
    int j0 = bid * 32 + (lane & 15);
    int jr0 = min(j0,      VOCAB - 1);
    int jr1 = min(j0 + 16, VOCAB - 1);
    const float*  wrow0 = W + (size_t)jr0 * 2048;
    const float*  wrow1 = W + (size_t)jr1 * 2048;
    const __bf16* arow  = A + (size_t)(lane & 15) * 2048;
    f32x4 acc[2][4] = {};
    for (int k0 = kbeg; k0 < kend; k0 += 32) {
        int kk = k0 + kg;
        float4 p0 = *(const float4*)(wrow0 + kk);
        float4 p1 = *(const float4*)(wrow0 + kk + 4);
        float4 q0 = *(const float4*)(wrow1 + kk);
        float4 q1 = *(const float4*)(wrow1 + kk + 4);
        bf16x8 bw0 = cvt8(p0, p1);
        bf16x8 bw1 = cvt8(q0, q1);
#pragma unroll
        for (int mt = 0; mt < 4; ++mt) {
            bf16x8 av = *(const bf16x8*)(arow + (size_t)mt * 16 * 2048 + kk);
            acc[0][mt] = __builtin_amdgcn_mfma_f32_16x16x32_bf16(av, bw0, acc[0][mt], 0, 0, 0);
            acc[1][mt] = __builtin_amdgcn_mfma_f32_16x16x32_bf16(av, bw1, acc[1][mt], 0, 0, 0);
        }
    }
    __shared__ float lds[4][1024];
    float Mreg = -INFINITY, Sreg = 0.f;
    for (int u = 0; u < ntiles; ++u) {
        if (u) __syncthreads();
#pragma unroll
        for (int mt = 0; mt < 4; ++mt)
#pragma unroll
            for (int r = 0; r < 4; ++r) {
                int m = mt * 16 + (lane >> 4) * 4 + r;
                lds[wid][m * 16 + (lane & 15)] = acc[u][mt][r];
            }
        __syncthreads();
#pragma unroll
        for (int o = tid; o < 1024; o += 256) {
            float s = lds[0][o] + lds[1][o] + lds[2][o] + lds[3][o];
            int m = o >> 4, jl = o & 15;
            int jj = bid * 32 + u * 16 + jl;
            s += bias[jj];
            out[(size_t)m * VOCAB + jj] = s;
            lds[0][o] = s;                       // each o owned by one thread
        }
        __syncthreads();
        if (tid < 64) {
            float mx = -INFINITY;
#pragma unroll
            for (int jl = 0; jl < 16; ++jl) mx = fmaxf(mx, lds[0][tid * 16 + jl]);
            float se = 0.f;
#pragma unroll
            for (int jl = 0; jl < 16; ++jl) se += expf(lds[0][tid * 16 + jl] - mx);
            float M2 = fmaxf(Mreg, mx);
            Sreg = Sreg * expf(Mreg - M2) + se * expf(mx - M2);
            Mreg = M2;
        }
    }
    if (tid < 64) {
        mw[(size_t)tid * NBLK + bid] = Mreg;
        sw[(size_t)tid * NBLK + bid] = Sreg;
    }
}

// Fused lse-combine + subtract. 832 blocks = 64 rows x 13 chunks of 4096.
__global__ __launch_bounds__(256) void k_lse_fused(float* __restrict__ logits,
                                                   const float* __restrict__ mw,
                                                   const float* __restrict__ sw) {
    int bid = blockIdx.x, tid = threadIdx.x;
    int b = bid / 13, c = bid % 13;
    const float* mrow = mw + (size_t)b * NBLK;
    const float* srow = sw + (size_t)b * NBLK;
    __shared__ float red[256];
    float m = -INFINITY;
    for (int i = tid; i < NBLK; i += 256) m = fmaxf(m, mrow[i]);
    red[tid] = m; __syncthreads();
    for (int off = 128; off; off >>= 1) { if (tid < off) red[tid] = fmaxf(red[tid], red[tid + off]); __syncthreads(); }
    m = red[0]; __syncthreads();
    float s = 0.f;
    for (int i = tid; i < NBLK; i += 256) s += srow[i] * expf(mrow[i] - m);
    red[tid] = s; __syncthreads();
    for (int off = 128; off; off >>= 1) { if (tid < off) red[tid] += red[tid + off]; __syncthreads(); }
    float lse = m + logf(red[0]);
    int base = c * 4096;
    int len  = min(4096, VOCAB - base);
    float* row = logits + (size_t)b * VOCAB + base;
    for (int i = tid * 4; i < len; i += 1024) {
        float4 x = *(float4*)(row + i);
        x.x -= lse; x.y -= lse; x.z -= lse; x.w -= lse;
        *(float4*)(row + i) = x;
    }
}

extern "C" void kernel_launch(void* const* d_in, const int* in_sizes, int n_in,
                              void* d_out, int out_size, void* d_ws, size_t ws_size,
                              hipStream_t stream) {
    const int*   last_output = (const int*)  d_in[0];
    const float* last_hidden = (const float*)d_in[1];
    const float* enc         = (const float*)d_in[2];
    const float* embedding   = (const float*)d_in[3];
    const float* attn_W      = (const float*)d_in[4];
    // d_in[5] = attn_b: t-independent -> cancels in softmax
    const float* v           = (const float*)d_in[6];
    const float* W_ih        = (const float*)d_in[7];
    const float* W_hh        = (const float*)d_in[8];
    const float* b_ih        = (const float*)d_in[9];
    const float* b_hh        = (const float*)d_in[10];
    const float* out_W       = (const float*)d_in[11];
    const float* out_b       = (const float*)d_in[12];

    float* out_logp = (float*)d_out;                         // [64][50000]
    float* out_hnew = (float*)d_out + (size_t)BATCH * VOCAB; // [64][1024]

    char* ws = (char*)d_ws;
    float*  u2p     = (float*) (ws + 0);          //  16 KB [4][1024]
    __bf16* x_bf    = (__bf16*)(ws + 16384);      // 192 KB [64][1536]
    __bf16* hid_bf  = (__bf16*)(ws + 212992);     // 128 KB [64][1024]
    __bf16* y_bf    = (__bf16*)(ws + 344064);     // 256 KB [64][2048]
    float*  Gi      = (float*) (ws + 606208);     // 768 KB [64][3072]
    float*  Gh      = (float*) (ws + 1392640);    // 768 KB
    float*  mw      = (float*) (ws + 2179072);    // 400 KB [64][1563]
    float*  sw      = (float*) (ws + 2579072);    // 400 KB

    k_u2_pack  <<<448,  256, 0, stream>>>(attn_W, v, u2p, last_output, embedding,
                                          last_hidden, x_bf, hid_bf);
    k_att_full <<<256,  256, 0, stream>>>(enc, u2p, x_bf, y_bf);
    k_gemm_gru <<<384,  256, 0, stream>>>(W_ih, b_ih, x_bf, Gi, W_hh, b_hh, hid_bf, Gh);
    k_combine  <<<256,  256, 0, stream>>>(Gi, Gh, last_hidden, out_hnew, y_bf);
    k_gemv     <<<NBLK, 256, 0, stream>>>(out_W, out_b, y_bf, out_logp, mw, sw);
    k_lse_fused<<<832,  256, 0, stream>>>(out_logp, mw, sw);
}

// Round 10
// 233.600 us; speedup vs baseline: 1.0504x; 1.0504x over previous
//
#include <hip/hip_runtime.h>
#include <cstddef>

#define VOCAB  50000
#define INPUT  512
#define HIDDEN 1024
#define BATCH  64
#define MAXLEN 256
#define NBLK   3125   // single 16-col tile per gemv block (50000 = 3125*16 exact)

typedef float  f32x4 __attribute__((ext_vector_type(4)));
typedef __bf16 bf16x8 __attribute__((ext_vector_type(8)));

__device__ __forceinline__ bf16x8 cvt8(float4 a, float4 b) {
    bf16x8 r;
    r[0] = (__bf16)a.x; r[1] = (__bf16)a.y; r[2] = (__bf16)a.z; r[3] = (__bf16)a.w;
    r[4] = (__bf16)b.x; r[5] = (__bf16)b.y; r[6] = (__bf16)b.z; r[7] = (__bf16)b.w;
    return r;
}

// u2 partials: 64 blocks = (hq 0..3, kc 0..15). Block: h in [hq*256,+256), k in [kc*64,+64).
__global__ void k_u2_part(const float* __restrict__ attn_W, const float* __restrict__ v,
                          float* __restrict__ u2p) {
    int bid = blockIdx.x, tid = threadIdx.x;
    int hq = bid >> 4, kc = bid & 15;
    int kl = tid & 63, hg = tid >> 6;
    int k = kc * 64 + kl;
    float acc = 0.f;
    int h0 = hq * 256 + hg * 64;
#pragma unroll 8
    for (int h = h0; h < h0 + 64; ++h)
        acc += v[h] * attn_W[(size_t)h * (2 * HIDDEN) + HIDDEN + k];
    __shared__ float red[4][64];
    red[hg][kl] = acc;
    __syncthreads();
    if (tid < 64)
        u2p[hq * 1024 + kc * 64 + tid] =
            red[0][tid] + red[1][tid] + red[2][tid] + red[3][tid];
}

// Flash attention pass: 256 blocks = (b, tq). Each handles 64 t's:
// scores (wave dot+reduce) -> block-local softmax partial (m,l) -> weighted ctx partial.
__global__ __launch_bounds__(256) void k_att(const float* __restrict__ enc,
                                             const float* __restrict__ u2p,
                                             float* __restrict__ mpart,
                                             float* __restrict__ lpart,
                                             float* __restrict__ ctxp) {
    int bid = blockIdx.x, tid = threadIdx.x;
    int b = bid >> 2, tq = bid & 3, t0 = tq * 64;
    __shared__ float u2s[1024];
    __shared__ float s_lds[64];
    __shared__ float p_lds[64];
    for (int i = tid; i < 1024; i += 256)
        u2s[i] = u2p[i] + u2p[1024 + i] + u2p[2048 + i] + u2p[3072 + i];
    __syncthreads();
    int w = tid >> 6, lane = tid & 63;
#pragma unroll 2
    for (int it = 0; it < 16; ++it) {
        int t = t0 + w * 16 + it;
        const float* row = enc + ((size_t)t * BATCH + b) * HIDDEN;
        float acc = 0.f;
#pragma unroll
        for (int i = 0; i < 4; ++i) {
            float4 e = *(const float4*)(row + lane * 4 + i * 256);
            float4 u = *(const float4*)(&u2s[lane * 4 + i * 256]);
            acc += e.x * u.x + e.y * u.y + e.z * u.z + e.w * u.w;
        }
#pragma unroll
        for (int off = 32; off; off >>= 1) acc += __shfl_down(acc, off, 64);
        if (lane == 0) s_lds[w * 16 + it] = acc;
    }
    __syncthreads();
    float m = -INFINITY;
#pragma unroll 8
    for (int t = 0; t < 64; ++t) m = fmaxf(m, s_lds[t]);
    if (tid < 64) p_lds[tid] = expf(s_lds[tid] - m);
    __syncthreads();
    float l = 0.f;
#pragma unroll 8
    for (int t = 0; t < 64; ++t) l += p_lds[t];
    float4 acc = {0.f, 0.f, 0.f, 0.f};
    const float* ebase = enc + ((size_t)t0 * BATCH + b) * HIDDEN + tid * 4;
#pragma unroll 4
    for (int t = 0; t < 64; ++t) {
        float p = p_lds[t];
        float4 e = *(const float4*)(ebase + (size_t)t * (BATCH * HIDDEN));
        acc.x += p * e.x; acc.y += p * e.y; acc.z += p * e.z; acc.w += p * e.w;
    }
    int o = b * 4 + tq;
    *(float4*)(ctxp + (size_t)o * 1024 + tid * 4) = acc;
    if (tid == 0) { mpart[o] = m; lpart[o] = l; }
}

// Combine 4 t-chunk partials -> context; pack context/emb/hid to bf16 buffers.
__global__ void k_att_comb(const float* __restrict__ mpart, const float* __restrict__ lpart,
                           const float* __restrict__ ctxp,
                           const int* __restrict__ last_output,
                           const float* __restrict__ embedding,
                           const float* __restrict__ hid,
                           __bf16* __restrict__ x_bf, __bf16* __restrict__ hid_bf,
                           __bf16* __restrict__ y_bf) {
    int b = blockIdx.x >> 2, hc = blockIdx.x & 3, tid = threadIdx.x;
    float m0 = mpart[b * 4 + 0], m1 = mpart[b * 4 + 1];
    float m2 = mpart[b * 4 + 2], m3 = mpart[b * 4 + 3];
    float M = fmaxf(fmaxf(m0, m1), fmaxf(m2, m3));
    float w0 = expf(m0 - M), w1 = expf(m1 - M), w2 = expf(m2 - M), w3 = expf(m3 - M);
    float denom = lpart[b * 4 + 0] * w0 + lpart[b * 4 + 1] * w1 +
                  lpart[b * 4 + 2] * w2 + lpart[b * 4 + 3] * w3;
    float inv = 1.f / denom;
    int h = hc * 256 + tid;
    const float* cp = ctxp + (size_t)b * 4096 + h;
    float c = (w0 * cp[0] + w1 * cp[1024] + w2 * cp[2048] + w3 * cp[3072]) * inv;
    x_bf[b * 1536 + INPUT + h]  = (__bf16)c;
    y_bf[b * 2048 + HIDDEN + h] = (__bf16)c;
    if (hc < 2)
        x_bf[b * 1536 + hc * 256 + tid] =
            (__bf16)embedding[(size_t)last_output[b] * INPUT + hc * 256 + tid];
    hid_bf[b * HIDDEN + hc * 256 + tid] = (__bf16)hid[b * HIDDEN + hc * 256 + tid];
}

// Small-M GEMM tile body: out[64, jt*16..+16] = A[64,K] @ W[N,K]^T + bias.
__device__ __forceinline__ void gemm_tile(const float* __restrict__ W,
                                          const float* __restrict__ bias,
                                          const __bf16* __restrict__ A,
                                          float* __restrict__ out,
                                          int N, int K, int jt, int tid) {
    int wid = tid >> 6, lane = tid & 63;
    int j  = jt * 16 + (lane & 15);
    int kg = (lane >> 4) * 8;
    int kchunk = K >> 2;
    int kbeg = wid * kchunk, kend = kbeg + kchunk;
    const float*  wrow = W + (size_t)j * K;
    const __bf16* arow = A + (size_t)(lane & 15) * K;
    f32x4 acc[4] = {};
    for (int k0 = kbeg; k0 < kend; k0 += 32) {
        int kk = k0 + kg;
        float4 w0 = *(const float4*)(wrow + kk);
        float4 w1 = *(const float4*)(wrow + kk + 4);
        bf16x8 bw = cvt8(w0, w1);
#pragma unroll
        for (int mt = 0; mt < 4; ++mt) {
            bf16x8 av = *(const bf16x8*)(arow + (size_t)mt * 16 * K + kk);
            acc[mt] = __builtin_amdgcn_mfma_f32_16x16x32_bf16(av, bw, acc[mt], 0, 0, 0);
        }
    }
    __shared__ float lds[4][1024];
#pragma unroll
    for (int mt = 0; mt < 4; ++mt)
#pragma unroll
        for (int r = 0; r < 4; ++r) {
            int m = mt * 16 + (lane >> 4) * 4 + r;
            lds[wid][m * 16 + (lane & 15)] = acc[mt][r];
        }
    __syncthreads();
#pragma unroll
    for (int o = tid; o < 1024; o += 256) {
        float s = lds[0][o] + lds[1][o] + lds[2][o] + lds[3][o];
        int m = o >> 4, jl = o & 15;
        out[(size_t)m * N + jt * 16 + jl] = s + bias[jt * 16 + jl];
    }
}

// GRU gate GEMMs, one dispatch: blocks 0..191 -> Gi (K=1536), 192..383 -> Gh (K=1024)
__global__ __launch_bounds__(256) void k_gemm_gru(const float* __restrict__ W_ih,
                                                  const float* __restrict__ b_ih,
                                                  const __bf16* __restrict__ x_bf,
                                                  float* __restrict__ Gi,
                                                  const float* __restrict__ W_hh,
                                                  const float* __restrict__ b_hh,
                                                  const __bf16* __restrict__ hid_bf,
                                                  float* __restrict__ Gh) {
    int bid = blockIdx.x, tid = threadIdx.x;
    if (bid < 192) gemm_tile(W_ih, b_ih, x_bf,  Gi, 3072, 1536, bid,       tid);
    else           gemm_tile(W_hh, b_hh, hid_bf, Gh, 3072, 1024, bid - 192, tid);
}

// GRU combine: h_new = (1-z)*n + z*h_prev
__global__ void k_combine(const float* __restrict__ Gi, const float* __restrict__ Gh,
                          const float* __restrict__ hid, float* __restrict__ hnew_out,
                          __bf16* __restrict__ y_bf) {
    int idx = blockIdx.x * 256 + threadIdx.x;   // 64*1024
    int b = idx >> 10, h = idx & 1023;
    const float* gi = Gi + (size_t)b * 3072;
    const float* gh = Gh + (size_t)b * 3072;
    float r  = 1.f / (1.f + expf(-(gi[h] + gh[h])));
    float z  = 1.f / (1.f + expf(-(gi[1024 + h] + gh[1024 + h])));
    float n  = tanhf(gi[2048 + h] + r * gh[2048 + h]);
    float hp = hid[b * HIDDEN + h];
    float hn = (1.f - z) * n + z * hp;
    hnew_out[b * HIDDEN + h] = hn;
    y_bf[b * 2048 + h] = (__bf16)hn;
}

// Vocab projection: 3125 single-tile blocks (exact, no clamps), plain loads,
// unroll-4 K-loop for deeper in-flight VMEM. Emits per-block (max,sumexp).
__global__ __launch_bounds__(256) void k_gemv(const float* __restrict__ W,
                                              const float* __restrict__ bias,
                                              const __bf16* __restrict__ A,
                                              float* __restrict__ out,
                                              float* __restrict__ mw,
                                              float* __restrict__ sw) {
    int bid = blockIdx.x, tid = threadIdx.x;
    int wid = tid >> 6, lane = tid & 63;
    int kg = (lane >> 4) * 8;
    int kbeg = wid * 512;                        // K=2048 over 4 waves
    int j = bid * 16 + (lane & 15);
    const float*  wrow = W + (size_t)j * 2048;
    const __bf16* arow = A + (size_t)(lane & 15) * 2048;
    f32x4 acc[4] = {};
#pragma unroll 4
    for (int k0 = kbeg; k0 < kbeg + 512; k0 += 32) {
        int kk = k0 + kg;
        float4 w0 = *(const float4*)(wrow + kk);
        float4 w1 = *(const float4*)(wrow + kk + 4);
        bf16x8 bw = cvt8(w0, w1);
#pragma unroll
        for (int mt = 0; mt < 4; ++mt) {
            bf16x8 av = *(const bf16x8*)(arow + (size_t)mt * 16 * 2048 + kk);
            acc[mt] = __builtin_amdgcn_mfma_f32_16x16x32_bf16(av, bw, acc[mt], 0, 0, 0);
        }
    }
    __shared__ float lds[4][1024];
#pragma unroll
    for (int mt = 0; mt < 4; ++mt)
#pragma unroll
        for (int r = 0; r < 4; ++r) {
            int m = mt * 16 + (lane >> 4) * 4 + r;
            lds[wid][m * 16 + (lane & 15)] = acc[mt][r];
        }
    __syncthreads();
#pragma unroll
    for (int o = tid; o < 1024; o += 256) {
        float s = lds[0][o] + lds[1][o] + lds[2][o] + lds[3][o];
        int m = o >> 4, jl = o & 15;
        int jj = bid * 16 + jl;
        s += bias[jj];
        out[(size_t)m * VOCAB + jj] = s;
        lds[0][o] = s;                           // each o owned by one thread
    }
    __syncthreads();
    if (tid < 64) {
        float mx = -INFINITY;
#pragma unroll
        for (int jl = 0; jl < 16; ++jl) mx = fmaxf(mx, lds[0][tid * 16 + jl]);
        float se = 0.f;
#pragma unroll
        for (int jl = 0; jl < 16; ++jl) se += expf(lds[0][tid * 16 + jl] - mx);
        mw[(size_t)tid * NBLK + bid] = mx;
        sw[(size_t)tid * NBLK + bid] = se;
    }
}

// Fused lse-combine + subtract. 832 blocks = 64 rows x 13 chunks of 4096.
__global__ __launch_bounds__(256) void k_lse_fused(float* __restrict__ logits,
                                                   const float* __restrict__ mw,
                                                   const float* __restrict__ sw) {
    int bid = blockIdx.x, tid = threadIdx.x;
    int b = bid / 13, c = bid % 13;
    const float* mrow = mw + (size_t)b * NBLK;
    const float* srow = sw + (size_t)b * NBLK;
    __shared__ float red[256];
    float m = -INFINITY;
    for (int i = tid; i < NBLK; i += 256) m = fmaxf(m, mrow[i]);
    red[tid] = m; __syncthreads();
    for (int off = 128; off; off >>= 1) { if (tid < off) red[tid] = fmaxf(red[tid], red[tid + off]); __syncthreads(); }
    m = red[0]; __syncthreads();
    float s = 0.f;
    for (int i = tid; i < NBLK; i += 256) s += srow[i] * expf(mrow[i] - m);
    red[tid] = s; __syncthreads();
    for (int off = 128; off; off >>= 1) { if (tid < off) red[tid] += red[tid + off]; __syncthreads(); }
    float lse = m + logf(red[0]);
    int base = c * 4096;
    int len  = min(4096, VOCAB - base);
    float* row = logits + (size_t)b * VOCAB + base;
    for (int i = tid * 4; i < len; i += 1024) {
        float4 x = *(float4*)(row + i);
        x.x -= lse; x.y -= lse; x.z -= lse; x.w -= lse;
        *(float4*)(row + i) = x;
    }
}

extern "C" void kernel_launch(void* const* d_in, const int* in_sizes, int n_in,
                              void* d_out, int out_size, void* d_ws, size_t ws_size,
                              hipStream_t stream) {
    const int*   last_output = (const int*)  d_in[0];
    const float* last_hidden = (const float*)d_in[1];
    const float* enc         = (const float*)d_in[2];
    const float* embedding   = (const float*)d_in[3];
    const float* attn_W      = (const float*)d_in[4];
    // d_in[5] = attn_b: t-independent -> cancels in softmax
    const float* v           = (const float*)d_in[6];
    const float* W_ih        = (const float*)d_in[7];
    const float* W_hh        = (const float*)d_in[8];
    const float* b_ih        = (const float*)d_in[9];
    const float* b_hh        = (const float*)d_in[10];
    const float* out_W       = (const float*)d_in[11];
    const float* out_b       = (const float*)d_in[12];

    float* out_logp = (float*)d_out;                         // [64][50000]
    float* out_hnew = (float*)d_out + (size_t)BATCH * VOCAB; // [64][1024]

    char* ws = (char*)d_ws;
    float*  u2p     = (float*) (ws + 0);          //  16 KB [4][1024]
    float*  mpart   = (float*) (ws + 16384);      //   1 KB [64][4]
    float*  lpart   = (float*) (ws + 17408);      //   1 KB
    float*  ctxp    = (float*) (ws + 18432);      //   1 MB [64][4][1024]
    __bf16* x_bf    = (__bf16*)(ws + 1067008);    // 192 KB [64][1536]
    __bf16* hid_bf  = (__bf16*)(ws + 1263616);    // 128 KB [64][1024]
    __bf16* y_bf    = (__bf16*)(ws + 1394688);    // 256 KB [64][2048]
    float*  Gi      = (float*) (ws + 1656832);    // 768 KB [64][3072]
    float*  Gh      = (float*) (ws + 2443264);    // 768 KB
    float*  mw      = (float*) (ws + 3229696);    // 800000 B [64][3125]
    float*  sw      = (float*) (ws + 4029696);    // 800000 B

    k_u2_part  <<<64,   256, 0, stream>>>(attn_W, v, u2p);
    k_att      <<<256,  256, 0, stream>>>(enc, u2p, mpart, lpart, ctxp);
    k_att_comb <<<256,  256, 0, stream>>>(mpart, lpart, ctxp, last_output, embedding,
                                          last_hidden, x_bf, hid_bf, y_bf);
    k_gemm_gru <<<384,  256, 0, stream>>>(W_ih, b_ih, x_bf, Gi, W_hh, b_hh, hid_bf, Gh);
    k_combine  <<<256,  256, 0, stream>>>(Gi, Gh, last_hidden, out_hnew, y_bf);
    k_gemv     <<<NBLK, 256, 0, stream>>>(out_W, out_b, y_bf, out_logp, mw, sw);
    k_lse_fused<<<832,  256, 0, stream>>>(out_logp, mw, sw);
}

// Round 11
// 194.406 us; speedup vs baseline: 1.2621x; 1.2016x over previous
//
#include <hip/hip_runtime.h>
#include <cstddef>

#define VOCAB  50000
#define INPUT  512
#define HIDDEN 1024
#define BATCH  64
#define MAXLEN 256
#define NBLK   782    // gemv blocks: 781 x 4 tiles + 1 x 1 tile (50000 = 781*64 + 16)

typedef float  f32x4 __attribute__((ext_vector_type(4)));
typedef __bf16 bf16x8 __attribute__((ext_vector_type(8)));

__device__ __forceinline__ bf16x8 cvt8(float4 a, float4 b) {
    bf16x8 r;
    r[0] = (__bf16)a.x; r[1] = (__bf16)a.y; r[2] = (__bf16)a.z; r[3] = (__bf16)a.w;
    r[4] = (__bf16)b.x; r[5] = (__bf16)b.y; r[6] = (__bf16)b.z; r[7] = (__bf16)b.w;
    return r;
}

// u2 partials: 64 blocks = (hq 0..3, kc 0..15). Block: h in [hq*256,+256), k in [kc*64,+64).
__global__ void k_u2_part(const float* __restrict__ attn_W, const float* __restrict__ v,
                          float* __restrict__ u2p) {
    int bid = blockIdx.x, tid = threadIdx.x;
    int hq = bid >> 4, kc = bid & 15;
    int kl = tid & 63, hg = tid >> 6;
    int k = kc * 64 + kl;
    float acc = 0.f;
    int h0 = hq * 256 + hg * 64;
#pragma unroll 8
    for (int h = h0; h < h0 + 64; ++h)
        acc += v[h] * attn_W[(size_t)h * (2 * HIDDEN) + HIDDEN + k];
    __shared__ float red[4][64];
    red[hg][kl] = acc;
    __syncthreads();
    if (tid < 64)
        u2p[hq * 1024 + kc * 64 + tid] =
            red[0][tid] + red[1][tid] + red[2][tid] + red[3][tid];
}

// Flash attention pass: 256 blocks = (b, tq). Each handles 64 t's:
// scores (wave dot+reduce) -> block-local softmax partial (m,l) -> weighted ctx partial.
__global__ __launch_bounds__(256) void k_att(const float* __restrict__ enc,
                                             const float* __restrict__ u2p,
                                             float* __restrict__ mpart,
                                             float* __restrict__ lpart,
                                             float* __restrict__ ctxp) {
    int bid = blockIdx.x, tid = threadIdx.x;
    int b = bid >> 2, tq = bid & 3, t0 = tq * 64;
    __shared__ float u2s[1024];
    __shared__ float s_lds[64];
    __shared__ float p_lds[64];
    for (int i = tid; i < 1024; i += 256)
        u2s[i] = u2p[i] + u2p[1024 + i] + u2p[2048 + i] + u2p[3072 + i];
    __syncthreads();
    int w = tid >> 6, lane = tid & 63;
#pragma unroll 2
    for (int it = 0; it < 16; ++it) {
        int t = t0 + w * 16 + it;
        const float* row = enc + ((size_t)t * BATCH + b) * HIDDEN;
        float acc = 0.f;
#pragma unroll
        for (int i = 0; i < 4; ++i) {
            float4 e = *(const float4*)(row + lane * 4 + i * 256);
            float4 u = *(const float4*)(&u2s[lane * 4 + i * 256]);
            acc += e.x * u.x + e.y * u.y + e.z * u.z + e.w * u.w;
        }
#pragma unroll
        for (int off = 32; off; off >>= 1) acc += __shfl_down(acc, off, 64);
        if (lane == 0) s_lds[w * 16 + it] = acc;
    }
    __syncthreads();
    float m = -INFINITY;
#pragma unroll 8
    for (int t = 0; t < 64; ++t) m = fmaxf(m, s_lds[t]);
    if (tid < 64) p_lds[tid] = expf(s_lds[tid] - m);
    __syncthreads();
    float l = 0.f;
#pragma unroll 8
    for (int t = 0; t < 64; ++t) l += p_lds[t];
    float4 acc = {0.f, 0.f, 0.f, 0.f};
    const float* ebase = enc + ((size_t)t0 * BATCH + b) * HIDDEN + tid * 4;
#pragma unroll 4
    for (int t = 0; t < 64; ++t) {
        float p = p_lds[t];
        float4 e = *(const float4*)(ebase + (size_t)t * (BATCH * HIDDEN));
        acc.x += p * e.x; acc.y += p * e.y; acc.z += p * e.z; acc.w += p * e.w;
    }
    int o = b * 4 + tq;
    *(float4*)(ctxp + (size_t)o * 1024 + tid * 4) = acc;
    if (tid == 0) { mpart[o] = m; lpart[o] = l; }
}

// Combine 4 t-chunk partials -> context; pack context/emb/hid to bf16 buffers.
__global__ void k_att_comb(const float* __restrict__ mpart, const float* __restrict__ lpart,
                           const float* __restrict__ ctxp,
                           const int* __restrict__ last_output,
                           const float* __restrict__ embedding,
                           const float* __restrict__ hid,
                           __bf16* __restrict__ x_bf, __bf16* __restrict__ hid_bf,
                           __bf16* __restrict__ y_bf) {
    int b = blockIdx.x >> 2, hc = blockIdx.x & 3, tid = threadIdx.x;
    float m0 = mpart[b * 4 + 0], m1 = mpart[b * 4 + 1];
    float m2 = mpart[b * 4 + 2], m3 = mpart[b * 4 + 3];
    float M = fmaxf(fmaxf(m0, m1), fmaxf(m2, m3));
    float w0 = expf(m0 - M), w1 = expf(m1 - M), w2 = expf(m2 - M), w3 = expf(m3 - M);
    float denom = lpart[b * 4 + 0] * w0 + lpart[b * 4 + 1] * w1 +
                  lpart[b * 4 + 2] * w2 + lpart[b * 4 + 3] * w3;
    float inv = 1.f / denom;
    int h = hc * 256 + tid;
    const float* cp = ctxp + (size_t)b * 4096 + h;
    float c = (w0 * cp[0] + w1 * cp[1024] + w2 * cp[2048] + w3 * cp[3072]) * inv;
    x_bf[b * 1536 + INPUT + h]  = (__bf16)c;
    y_bf[b * 2048 + HIDDEN + h] = (__bf16)c;
    if (hc < 2)
        x_bf[b * 1536 + hc * 256 + tid] =
            (__bf16)embedding[(size_t)last_output[b] * INPUT + hc * 256 + tid];
    hid_bf[b * HIDDEN + hc * 256 + tid] = (__bf16)hid[b * HIDDEN + hc * 256 + tid];
}

// Small-M GEMM tile body: out[64, jt*16..+16] = A[64,K] @ W[N,K]^T + bias.
__device__ __forceinline__ void gemm_tile(const float* __restrict__ W,
                                          const float* __restrict__ bias,
                                          const __bf16* __restrict__ A,
                                          float* __restrict__ out,
                                          int N, int K, int jt, int tid) {
    int wid = tid >> 6, lane = tid & 63;
    int j  = jt * 16 + (lane & 15);
    int kg = (lane >> 4) * 8;
    int kchunk = K >> 2;
    int kbeg = wid * kchunk, kend = kbeg + kchunk;
    const float*  wrow = W + (size_t)j * K;
    const __bf16* arow = A + (size_t)(lane & 15) * K;
    f32x4 acc[4] = {};
    for (int k0 = kbeg; k0 < kend; k0 += 32) {
        int kk = k0 + kg;
        float4 w0 = *(const float4*)(wrow + kk);
        float4 w1 = *(const float4*)(wrow + kk + 4);
        bf16x8 bw = cvt8(w0, w1);
#pragma unroll
        for (int mt = 0; mt < 4; ++mt) {
            bf16x8 av = *(const bf16x8*)(arow + (size_t)mt * 16 * K + kk);
            acc[mt] = __builtin_amdgcn_mfma_f32_16x16x32_bf16(av, bw, acc[mt], 0, 0, 0);
        }
    }
    __shared__ float lds[4][1024];
#pragma unroll
    for (int mt = 0; mt < 4; ++mt)
#pragma unroll
        for (int r = 0; r < 4; ++r) {
            int m = mt * 16 + (lane >> 4) * 4 + r;
            lds[wid][m * 16 + (lane & 15)] = acc[mt][r];
        }
    __syncthreads();
#pragma unroll
    for (int o = tid; o < 1024; o += 256) {
        float s = lds[0][o] + lds[1][o] + lds[2][o] + lds[3][o];
        int m = o >> 4, jl = o & 15;
        out[(size_t)m * N + jt * 16 + jl] = s + bias[jt * 16 + jl];
    }
}

// GRU gate GEMMs, one dispatch: blocks 0..191 -> Gi (K=1536), 192..383 -> Gh (K=1024)
__global__ __launch_bounds__(256) void k_gemm_gru(const float* __restrict__ W_ih,
                                                  const float* __restrict__ b_ih,
                                                  const __bf16* __restrict__ x_bf,
                                                  float* __restrict__ Gi,
                                                  const float* __restrict__ W_hh,
                                                  const float* __restrict__ b_hh,
                                                  const __bf16* __restrict__ hid_bf,
                                                  float* __restrict__ Gh) {
    int bid = blockIdx.x, tid = threadIdx.x;
    if (bid < 192) gemm_tile(W_ih, b_ih, x_bf,  Gi, 3072, 1536, bid,       tid);
    else           gemm_tile(W_hh, b_hh, hid_bf, Gh, 3072, 1024, bid - 192, tid);
}

// GRU combine: h_new = (1-z)*n + z*h_prev
__global__ void k_combine(const float* __restrict__ Gi, const float* __restrict__ Gh,
                          const float* __restrict__ hid, float* __restrict__ hnew_out,
                          __bf16* __restrict__ y_bf) {
    int idx = blockIdx.x * 256 + threadIdx.x;   // 64*1024
    int b = idx >> 10, h = idx & 1023;
    const float* gi = Gi + (size_t)b * 3072;
    const float* gh = Gh + (size_t)b * 3072;
    float r  = 1.f / (1.f + expf(-(gi[h] + gh[h])));
    float z  = 1.f / (1.f + expf(-(gi[1024 + h] + gh[1024 + h])));
    float n  = tanhf(gi[2048 + h] + r * gh[2048 + h]);
    float hp = hid[b * HIDDEN + h];
    float hn = (1.f - z) * n + z * hp;
    hnew_out[b * HIDDEN + h] = hn;
    y_bf[b * 2048 + h] = (__bf16)hn;
}

// Vocab projection: 782 blocks x 4 16-col tiles (last block 1 tile).
// Shared A-fragment across 4 tiles quarters A-side L2 traffic vs single-tile.
// Plain loads (nt banned). Emits one online (max,sumexp) partial per (row, block).
__global__ __launch_bounds__(256) void k_gemv(const float* __restrict__ W,
                                              const float* __restrict__ bias,
                                              const __bf16* __restrict__ A,
                                              float* __restrict__ out,
                                              float* __restrict__ mw,
                                              float* __restrict__ sw) {
    int bid = blockIdx.x, tid = threadIdx.x;
    int wid = tid >> 6, lane = tid & 63;
    int kg = (lane >> 4) * 8;
    int kbeg = wid * 512;                        // K=2048 over 4 waves
    int ntiles = (bid == NBLK - 1) ? 1 : 4;
    int j0 = bid * 64 + (lane & 15);
    const float* wrow0 = W + (size_t)min(j0,      VOCAB - 1) * 2048;
    const float* wrow1 = W + (size_t)min(j0 + 16, VOCAB - 1) * 2048;
    const float* wrow2 = W + (size_t)min(j0 + 32, VOCAB - 1) * 2048;
    const float* wrow3 = W + (size_t)min(j0 + 48, VOCAB - 1) * 2048;
    const __bf16* arow = A + (size_t)(lane & 15) * 2048;
    f32x4 acc[4][4] = {};
    for (int k0 = kbeg; k0 < kbeg + 512; k0 += 32) {
        int kk = k0 + kg;
        bf16x8 bw0 = cvt8(*(const float4*)(wrow0 + kk), *(const float4*)(wrow0 + kk + 4));
        bf16x8 bw1 = cvt8(*(const float4*)(wrow1 + kk), *(const float4*)(wrow1 + kk + 4));
        bf16x8 bw2 = cvt8(*(const float4*)(wrow2 + kk), *(const float4*)(wrow2 + kk + 4));
        bf16x8 bw3 = cvt8(*(const float4*)(wrow3 + kk), *(const float4*)(wrow3 + kk + 4));
#pragma unroll
        for (int mt = 0; mt < 4; ++mt) {
            bf16x8 av = *(const bf16x8*)(arow + (size_t)mt * 16 * 2048 + kk);
            acc[0][mt] = __builtin_amdgcn_mfma_f32_16x16x32_bf16(av, bw0, acc[0][mt], 0, 0, 0);
            acc[1][mt] = __builtin_amdgcn_mfma_f32_16x16x32_bf16(av, bw1, acc[1][mt], 0, 0, 0);
            acc[2][mt] = __builtin_amdgcn_mfma_f32_16x16x32_bf16(av, bw2, acc[2][mt], 0, 0, 0);
            acc[3][mt] = __builtin_amdgcn_mfma_f32_16x16x32_bf16(av, bw3, acc[3][mt], 0, 0, 0);
        }
    }
    __shared__ float lds[4][1024];
    float Mreg = -INFINITY, Sreg = 0.f;
    for (int u = 0; u < ntiles; ++u) {
        if (u) __syncthreads();
#pragma unroll
        for (int mt = 0; mt < 4; ++mt)
#pragma unroll
            for (int r = 0; r < 4; ++r) {
                int m = mt * 16 + (lane >> 4) * 4 + r;
                lds[wid][m * 16 + (lane & 15)] = acc[u][mt][r];
            }
        __syncthreads();
#pragma unroll
        for (int o = tid; o < 1024; o += 256) {
            float s = lds[0][o] + lds[1][o] + lds[2][o] + lds[3][o];
            int m = o >> 4, jl = o & 15;
            int jj = bid * 64 + u * 16 + jl;
            s += bias[jj];
            out[(size_t)m * VOCAB + jj] = s;
            lds[0][o] = s;                       // each o owned by one thread
        }
        __syncthreads();
        if (tid < 64) {
            float mx = -INFINITY;
#pragma unroll
            for (int jl = 0; jl < 16; ++jl) mx = fmaxf(mx, lds[0][tid * 16 + jl]);
            float se = 0.f;
#pragma unroll
            for (int jl = 0; jl < 16; ++jl) se += expf(lds[0][tid * 16 + jl] - mx);
            float M2 = fmaxf(Mreg, mx);
            Sreg = Sreg * expf(Mreg - M2) + se * expf(mx - M2);
            Mreg = M2;
        }
    }
    if (tid < 64) {
        mw[(size_t)tid * NBLK + bid] = Mreg;
        sw[(size_t)tid * NBLK + bid] = Sreg;
    }
}

// Fused lse-combine + subtract. 832 blocks = 64 rows x 13 chunks of 4096.
__global__ __launch_bounds__(256) void k_lse_fused(float* __restrict__ logits,
                                                   const float* __restrict__ mw,
                                                   const float* __restrict__ sw) {
    int bid = blockIdx.x, tid = threadIdx.x;
    int b = bid / 13, c = bid % 13;
    const float* mrow = mw + (size_t)b * NBLK;
    const float* srow = sw + (size_t)b * NBLK;
    __shared__ float red[256];
    float m = -INFINITY;
    for (int i = tid; i < NBLK; i += 256) m = fmaxf(m, mrow[i]);
    red[tid] = m; __syncthreads();
    for (int off = 128; off; off >>= 1) { if (tid < off) red[tid] = fmaxf(red[tid], red[tid + off]); __syncthreads(); }
    m = red[0]; __syncthreads();
    float s = 0.f;
    for (int i = tid; i < NBLK; i += 256) s += srow[i] * expf(mrow[i] - m);
    red[tid] = s; __syncthreads();
    for (int off = 128; off; off >>= 1) { if (tid < off) red[tid] += red[tid + off]; __syncthreads(); }
    float lse = m + logf(red[0]);
    int base = c * 4096;
    int len  = min(4096, VOCAB - base);
    float* row = logits + (size_t)b * VOCAB + base;
    for (int i = tid * 4; i < len; i += 1024) {
        float4 x = *(float4*)(row + i);
        x.x -= lse; x.y -= lse; x.z -= lse; x.w -= lse;
        *(float4*)(row + i) = x;
    }
}

extern "C" void kernel_launch(void* const* d_in, const int* in_sizes, int n_in,
                              void* d_out, int out_size, void* d_ws, size_t ws_size,
                              hipStream_t stream) {
    const int*   last_output = (const int*)  d_in[0];
    const float* last_hidden = (const float*)d_in[1];
    const float* enc         = (const float*)d_in[2];
    const float* embedding   = (const float*)d_in[3];
    const float* attn_W      = (const float*)d_in[4];
    // d_in[5] = attn_b: t-independent -> cancels in softmax
    const float* v           = (const float*)d_in[6];
    const float* W_ih        = (const float*)d_in[7];
    const float* W_hh        = (const float*)d_in[8];
    const float* b_ih        = (const float*)d_in[9];
    const float* b_hh        = (const float*)d_in[10];
    const float* out_W       = (const float*)d_in[11];
    const float* out_b       = (const float*)d_in[12];

    float* out_logp = (float*)d_out;                         // [64][50000]
    float* out_hnew = (float*)d_out + (size_t)BATCH * VOCAB; // [64][1024]

    char* ws = (char*)d_ws;
    float*  u2p     = (float*) (ws + 0);          //  16 KB [4][1024]
    float*  mpart   = (float*) (ws + 16384);      //   1 KB [64][4]
    float*  lpart   = (float*) (ws + 17408);      //   1 KB
    float*  ctxp    = (float*) (ws + 18432);      //   1 MB [64][4][1024]
    __bf16* x_bf    = (__bf16*)(ws + 1067008);    // 192 KB [64][1536]
    __bf16* hid_bf  = (__bf16*)(ws + 1263616);    // 128 KB [64][1024]
    __bf16* y_bf    = (__bf16*)(ws + 1394688);    // 256 KB [64][2048]
    float*  Gi      = (float*) (ws + 1656832);    // 768 KB [64][3072]
    float*  Gh      = (float*) (ws + 2443264);    // 768 KB
    float*  mw      = (float*) (ws + 3229696);    // 200 KB [64][782]
    float*  sw      = (float*) (ws + 3429696);    // 200 KB

    k_u2_part  <<<64,   256, 0, stream>>>(attn_W, v, u2p);
    k_att      <<<256,  256, 0, stream>>>(enc, u2p, mpart, lpart, ctxp);
    k_att_comb <<<256,  256, 0, stream>>>(mpart, lpart, ctxp, last_output, embedding,
                                          last_hidden, x_bf, hid_bf, y_bf);
    k_gemm_gru <<<384,  256, 0, stream>>>(W_ih, b_ih, x_bf, Gi, W_hh, b_hh, hid_bf, Gh);
    k_combine  <<<256,  256, 0, stream>>>(Gi, Gh, last_hidden, out_hnew, y_bf);
    k_gemv     <<<NBLK, 256, 0, stream>>>(out_W, out_b, y_bf, out_logp, mw, sw);
    k_lse_fused<<<832,  256, 0, stream>>>(out_logp, mw, sw);
}